// Round 9
// baseline (192.886 us; speedup 1.0000x reference)
//
#include <hip/hip_runtime.h>
#include <hip/hip_bf16.h>
#include <cmath>

#define BATCH 32
#define H_IN 56
#define W_IN 56
#define N_IN (H_IN * W_IN)   // 3136
#define LKV 784              // 28*28 pooled kv length
#define LKV_PAD 864          // 27 tiles of 32
#define FRAG_ELEMS 82944     // per-batch K/V frag buffer elems (27*6*512)

typedef short bf16x8 __attribute__((ext_vector_type(8)));
typedef float f32x4 __attribute__((ext_vector_type(4)));
typedef float f32x16 __attribute__((ext_vector_type(16)));

__device__ __forceinline__ unsigned pack_bf16(float a, float b) {
    unsigned ua = __builtin_bit_cast(unsigned, a);
    unsigned ub = __builtin_bit_cast(unsigned, b);
    ua = (ua + 0x7FFFu + ((ua >> 16) & 1u)) >> 16;
    ub = (ub + 0x7FFFu + ((ub >> 16) & 1u)) >> 16;
    return ua | (ub << 16);
}

__device__ __forceinline__ unsigned short cvt_bf16(float a) {
    unsigned ua = __builtin_bit_cast(unsigned, a);
    return (unsigned short)((ua + 0x7FFFu + ((ua >> 16) & 1u)) >> 16);
}

__device__ __forceinline__ float bf16_to_f32(unsigned short u) {
    unsigned v = ((unsigned)u) << 16;
    return __builtin_bit_cast(float, v);
}

__device__ __forceinline__ float bflo(unsigned u) {
    return __builtin_bit_cast(float, u << 16);
}
__device__ __forceinline__ float bfhi(unsigned u) {
    return __builtin_bit_cast(float, u & 0xFFFF0000u);
}

// [lo16 = trunc-bf16(a), hi16 = trunc-bf16(b)] in one v_perm
__device__ __forceinline__ unsigned pack_trunc(float a, float b) {
    return __builtin_amdgcn_perm(__builtin_bit_cast(unsigned, b),
                                 __builtin_bit_cast(unsigned, a), 0x07060302u);
}

__device__ __forceinline__ f32x16 zero16() {
    f32x16 z;
#pragma unroll
    for (int i = 0; i < 16; ++i) z[i] = 0.f;
    return z;
}

// ---------------------------------------------------------------------------
// One-time weight prep:
//  idx <  3456 : Wqkv fp32 [288][96] -> bf16 A-frag order (54 frags)
//  idx <  4608 : Wproj fp32 [96][96] -> bf16 A-frag order (18 frags)
//  idx <  7200 : pool conv weights [96][9] -> transposed fp32 [3][9][96]
// ---------------------------------------------------------------------------
__global__ __launch_bounds__(256) void wprep_kernel(
    const float* __restrict__ Wqkv, const float* __restrict__ Wproj,
    const float* __restrict__ pqw, const float* __restrict__ pkw,
    const float* __restrict__ pvw,
    unsigned short* __restrict__ wq, unsigned short* __restrict__ wp,
    float* __restrict__ wpool)
{
    int idx = blockIdx.x * 256 + threadIdx.x;
    if (idx < 4608) {
        const float* src; unsigned short* dst; int li;
        if (idx < 3456) { src = Wqkv; dst = wq; li = idx; }
        else            { src = Wproj; dst = wp; li = idx - 3456; }
        int frag = li >> 6, ln = li & 63;
        int ct = frag / 3, kkb = frag % 3;
        int ch = ct * 16 + (ln & 15);
        int k0 = kkb * 32 + (ln >> 4) * 8;
        const float* s = src + ch * 96 + k0;
        float4 v0 = *reinterpret_cast<const float4*>(s);
        float4 v1 = *reinterpret_cast<const float4*>(s + 4);
        uint4 o;
        o.x = pack_bf16(v0.x, v0.y); o.y = pack_bf16(v0.z, v0.w);
        o.z = pack_bf16(v1.x, v1.y); o.w = pack_bf16(v1.z, v1.w);
        *reinterpret_cast<uint4*>(dst + (size_t)li * 8) = o;
    } else if (idx < 7200) {
        int li = idx - 4608;               // 0..2591
        int which = li / 864, r = li % 864;
        int tap = r / 96, c = r % 96;
        const float* src = (which == 0) ? pqw : (which == 1 ? pkw : pvw);
        wpool[which * 864 + tap * 96 + c] = src[c * 9 + tap];
    }
}

// ---------------------------------------------------------------------------
// MFMA GEMM v2: out[t][n] = sum_k X[t][k]*W[n][k] + bias[n]
// 256 thr / 4 waves; 256 tokens per block (64/wave = 4 iters x 16).
// ---------------------------------------------------------------------------
template <int NCT, bool IN_BF16, bool OUT_F32>
__global__ __launch_bounds__(256, 2) void gemm2_kernel(
    const void* __restrict__ Xv, const unsigned short* __restrict__ Wfr,
    const float* __restrict__ bias, void* __restrict__ o0,
    void* __restrict__ o1, void* __restrict__ o2)
{
    __shared__ unsigned short Wl[NCT * 192 * 8];
    const int tid = threadIdx.x;
    const int wid = tid >> 6, lane = tid & 63;
    const int lo16 = lane & 15, hi = lane >> 4;

    for (int idx = tid; idx < NCT * 192; idx += 256)
        *reinterpret_cast<int4*>(&Wl[idx * 8]) =
            *reinterpret_cast<const int4*>(Wfr + (size_t)idx * 8);

    const size_t tok0 = (size_t)blockIdx.x * 256 + wid * 64;
    bf16x8 xb[12];
#pragma unroll
    for (int it = 0; it < 4; ++it) {
        size_t t = tok0 + it * 16 + lo16;
#pragma unroll
        for (int kkb = 0; kkb < 3; ++kkb) {
            if constexpr (IN_BF16) {
                xb[it * 3 + kkb] = *reinterpret_cast<const bf16x8*>(
                    (const unsigned short*)Xv + t * 96 + kkb * 32 + hi * 8);
            } else {
                const float* xp = (const float*)Xv + t * 96 + kkb * 32 + hi * 8;
                float4 a = *reinterpret_cast<const float4*>(xp);
                float4 c = *reinterpret_cast<const float4*>(xp + 4);
                uint4 u;
                u.x = pack_bf16(a.x, a.y); u.y = pack_bf16(a.z, a.w);
                u.z = pack_bf16(c.x, c.y); u.w = pack_bf16(c.z, c.w);
                xb[it * 3 + kkb] = __builtin_bit_cast(bf16x8, u);
            }
        }
    }
    __syncthreads();

#pragma unroll
    for (int ct = 0; ct < NCT; ++ct) {
        bf16x8 wf[3];
#pragma unroll
        for (int kkb = 0; kkb < 3; ++kkb)
            wf[kkb] = *reinterpret_cast<const bf16x8*>(&Wl[((ct * 3 + kkb) * 64 + lane) * 8]);
        const int chb = ct * 16 + hi * 4;
        float4 bv = *reinterpret_cast<const float4*>(bias + chb);
#pragma unroll
        for (int it = 0; it < 4; ++it) {
            f32x4 a = (f32x4){0.f, 0.f, 0.f, 0.f};
#pragma unroll
            for (int kkb = 0; kkb < 3; ++kkb)
                a = __builtin_amdgcn_mfma_f32_16x16x32_bf16(wf[kkb], xb[it * 3 + kkb], a, 0, 0, 0);
            size_t t = tok0 + it * 16 + lo16;
            float r0 = a[0] + bv.x, r1 = a[1] + bv.y;
            float r2 = a[2] + bv.z, r3 = a[3] + bv.w;
            if constexpr (OUT_F32) {
                *reinterpret_cast<float4*>((float*)o0 + t * 96 + chb) =
                    make_float4(r0, r1, r2, r3);
            } else {
                unsigned short* ob =
                    (unsigned short*)((ct < 6) ? o0 : (ct < 12 ? o1 : o2));
                int lch = (ct % 6) * 16 + hi * 4;
                uint2 p;
                p.x = pack_bf16(r0, r1);
                p.y = pack_bf16(r2, r3);
                *reinterpret_cast<uint2*>(ob + t * 96 + lch) = p;
            }
        }
    }
}

// ---------------------------------------------------------------------------
// Pool v4: depthwise 3x3 conv (pad 1) + LayerNorm, bf16 in / bf16 out.
// Block = 192 threads = 16 tokens x 12 chunk-threads (8 ch each).
// OMODE 0: row-major [B][Lp][96] (q). OMODE 1: K MFMA-frag order.
// OMODE 2: V^T MFMA-frag order. For OMODE 1/2 the token space is padded to
// LpPad=864/batch; pad tokens write ZERO frags (consumed as masked pads).
// ---------------------------------------------------------------------------
template <int OMODE, int STRIDE>
__global__ __launch_bounds__(192) void pool_ln4_kernel(
    const unsigned short* __restrict__ in, const float* __restrict__ pwt,
    const float* __restrict__ g, const float* __restrict__ beta,
    unsigned short* __restrict__ out, int Hp, int Wp, int LpPad, float oscale)
{
    __shared__ float2 part[192];
    __shared__ float2 mrs[16];
    const int tid = threadIdx.x;
    const int tok_l = tid / 12, c8 = tid % 12;
    const int gt = blockIdx.x * 16 + tok_l;
    const int Lp = Hp * Wp;
    const int b = gt / LpPad, rem = gt % LpPad;
    const bool pad = (rem >= Lp);
    const int yo = rem / Wp, xo = rem % Wp;

    float wt[9][8];
#pragma unroll
    for (int tap = 0; tap < 9; ++tap) {
        float4 w0 = *reinterpret_cast<const float4*>(pwt + tap * 96 + c8 * 8);
        float4 w1 = *reinterpret_cast<const float4*>(pwt + tap * 96 + c8 * 8 + 4);
        wt[tap][0] = w0.x; wt[tap][1] = w0.y; wt[tap][2] = w0.z; wt[tap][3] = w0.w;
        wt[tap][4] = w1.x; wt[tap][5] = w1.y; wt[tap][6] = w1.z; wt[tap][7] = w1.w;
    }

    float acc[8];
#pragma unroll
    for (int j = 0; j < 8; ++j) acc[j] = 0.f;

    const unsigned short* ib = in + (size_t)b * (H_IN * W_IN * 96) + c8 * 8;
#pragma unroll
    for (int dy = 0; dy < 3; ++dy) {
        const int iy = yo * STRIDE + dy - 1;
        if ((unsigned)iy < (unsigned)H_IN) {
#pragma unroll
            for (int dx = 0; dx < 3; ++dx) {
                const int ix = xo * STRIDE + dx - 1;
                if ((unsigned)ix < (unsigned)W_IN) {
                    const int tap = dy * 3 + dx;
                    uint4 d = *reinterpret_cast<const uint4*>(
                        ib + ((size_t)iy * W_IN + ix) * 96);
                    acc[0] += bflo(d.x) * wt[tap][0];
                    acc[1] += bfhi(d.x) * wt[tap][1];
                    acc[2] += bflo(d.y) * wt[tap][2];
                    acc[3] += bfhi(d.y) * wt[tap][3];
                    acc[4] += bflo(d.z) * wt[tap][4];
                    acc[5] += bfhi(d.z) * wt[tap][5];
                    acc[6] += bflo(d.w) * wt[tap][6];
                    acc[7] += bfhi(d.w) * wt[tap][7];
                }
            }
        }
    }

    float s = 0.f, s2 = 0.f;
#pragma unroll
    for (int j = 0; j < 8; ++j) { s += acc[j]; s2 += acc[j] * acc[j]; }
    part[tid] = make_float2(s, s2);
    __syncthreads();
    if (tid < 16) {
        float a = 0.f, q = 0.f;
#pragma unroll
        for (int j = 0; j < 12; ++j) {
            float2 p = part[tid * 12 + j];
            a += p.x; q += p.y;
        }
        float mu = a * (1.f / 96.f);
        float var = q * (1.f / 96.f) - mu * mu;
        mrs[tid] = make_float2(mu, rsqrtf(var + 1e-6f));
    }
    __syncthreads();
    const float mu = mrs[tok_l].x, rstd = mrs[tok_l].y;

    float4 g0 = *reinterpret_cast<const float4*>(g + c8 * 8);
    float4 g1 = *reinterpret_cast<const float4*>(g + c8 * 8 + 4);
    float4 b0 = *reinterpret_cast<const float4*>(beta + c8 * 8);
    float4 b1 = *reinterpret_cast<const float4*>(beta + c8 * 8 + 4);
    float r[8];
    r[0] = (acc[0] - mu) * rstd * (g0.x * oscale) + b0.x * oscale;
    r[1] = (acc[1] - mu) * rstd * (g0.y * oscale) + b0.y * oscale;
    r[2] = (acc[2] - mu) * rstd * (g0.z * oscale) + b0.z * oscale;
    r[3] = (acc[3] - mu) * rstd * (g0.w * oscale) + b0.w * oscale;
    r[4] = (acc[4] - mu) * rstd * (g1.x * oscale) + b1.x * oscale;
    r[5] = (acc[5] - mu) * rstd * (g1.y * oscale) + b1.y * oscale;
    r[6] = (acc[6] - mu) * rstd * (g1.z * oscale) + b1.z * oscale;
    r[7] = (acc[7] - mu) * rstd * (g1.w * oscale) + b1.w * oscale;
    if (OMODE != 0 && pad) {
#pragma unroll
        for (int j = 0; j < 8; ++j) r[j] = 0.f;
    }

    if constexpr (OMODE == 0) {
        uint4 o;
        o.x = pack_bf16(r[0], r[1]); o.y = pack_bf16(r[2], r[3]);
        o.z = pack_bf16(r[4], r[5]); o.w = pack_bf16(r[6], r[7]);
        *reinterpret_cast<uint4*>(out + (size_t)gt * 96 + c8 * 8) = o;
    } else if constexpr (OMODE == 1) {
        // K frag order: frag(t=kv/32, kkb), lane = (kv&31)|(hi<<5); 16B/thread
        int t = rem >> 5, kkb = c8 >> 1, hi = c8 & 1;
        int ln = (rem & 31) | (hi << 5);
        uint4 o;
        o.x = pack_bf16(r[0], r[1]); o.y = pack_bf16(r[2], r[3]);
        o.z = pack_bf16(r[4], r[5]); o.w = pack_bf16(r[6], r[7]);
        *reinterpret_cast<uint4*>(out + (size_t)b * FRAG_ELEMS +
                                  ((size_t)(t * 6 + kkb) * 64 + ln) * 8) = o;
    } else {
        // V^T frag order: frag(kv16, ct), lane=(ch&31)|(lh<<5), elem = kv&7
        int kv16 = rem >> 4, e = rem & 7, lh = (rem >> 3) & 1;
#pragma unroll
        for (int j = 0; j < 8; ++j) {
            int j8 = c8 * 8 + j;
            int ct = j8 >> 5;
            int ln = (j8 & 31) | (lh << 5);
            out[(size_t)b * FRAG_ELEMS + ((size_t)(kv16 * 3 + ct) * 64 + ln) * 8 + e] =
                cvt_bf16(r[j]);
        }
    }
}

// ---------------------------------------------------------------------------
// MFMA flash attention v6 + residual (bf16 out). kv-split across 4 waves:
// block = 256 thr / 4 waves, all waves share one 32-q tile; wave w computes
// kv tiles t = w, w+4, ... (6-7 of 25). Fixed-m softmax => partials combine
// by pure addition: waves 1-3 store acc+l to LDS (SoA, lane-linear,
// conflict-free), one barrier, wave 0 sums and runs the epilogue.
// 4x shorter per-wave dependency chain, 4x the wave count (16 waves/CU
// resident at 37 KB LDS) -- the latency-bound fix.
// ---------------------------------------------------------------------------
__global__ __launch_bounds__(256) void attn_mfma6_kernel(
    const unsigned short* __restrict__ qpl, const unsigned short* __restrict__ Kf,
    const unsigned short* __restrict__ Vf, unsigned short* __restrict__ out)
{
    __shared__ float partial[3][49][64];           // 37632 B

    const int bid = blockIdx.x;                    // 0..3135
    const int swz = (bid & 7) * 392 + (bid >> 3);  // XCD grouping (3136%8==0)
    const int b = swz / 98, qblk = swz % 98;
    const int tid = threadIdx.x;
    const int wid = tid >> 6;
    const int lane = tid & 63;
    const int l31 = lane & 31, h = lane >> 5;

    const int qrow = qblk * 32 + l31;
    const unsigned short* qptr = qpl + ((size_t)b * N_IN + qrow) * 96;
    bf16x8 qf[6];
#pragma unroll
    for (int kkb = 0; kkb < 6; ++kkb)
        qf[kkb] = *reinterpret_cast<const bf16x8*>(qptr + kkb * 16 + h * 8);

    f32x16 a0 = zero16(), a1 = zero16(), a2 = zero16();
    float lsum = 0.f;

    const unsigned short* Kb = Kf + (size_t)b * FRAG_ELEMS;
    const unsigned short* Vb = Vf + (size_t)b * FRAG_ELEMS;

    for (int t = wid; t < 25; t += 4) {
        // K fragments for this 32-kv tile (6 x 16B lane-linear loads)
        bf16x8 kf[6];
#pragma unroll
        for (int kkb = 0; kkb < 6; ++kkb)
            kf[kkb] = *reinterpret_cast<const bf16x8*>(
                Kb + ((size_t)(t * 6 + kkb) * 64 + lane) * 8);

        __builtin_amdgcn_s_setprio(1);
        f32x16 s = zero16();
#pragma unroll
        for (int kkb = 0; kkb < 6; ++kkb)
            s = __builtin_amdgcn_mfma_f32_32x32x16_bf16(kf[kkb], qf[kkb], s, 0, 0, 0);
        __builtin_amdgcn_s_setprio(0);

        // V fragments (issued before softmax VALU to hide L2 latency)
        bf16x8 v0[3], v1[3];
#pragma unroll
        for (int ct = 0; ct < 3; ++ct) {
            v0[ct] = *reinterpret_cast<const bf16x8*>(
                Vb + ((size_t)((2 * t) * 3 + ct) * 64 + lane) * 8);
            v1[ct] = *reinterpret_cast<const bf16x8*>(
                Vb + ((size_t)((2 * t + 1) * 3 + ct) * 64 + lane) * 8);
        }

        // softmax (fixed-m): p = exp2(s) via v_exp, truncated to bf16
        const bool full = (t < 24);
        unsigned d[8], sw[8];
        {
            float p[16];
#pragma unroll
            for (int r = 0; r < 16; ++r) {
                float e = __builtin_amdgcn_exp2f(s[r]);
                p[r] = __builtin_bit_cast(float,
                         __builtin_bit_cast(unsigned, e) & 0xFFFF0000u);
            }
            float q0 = 0.f, q1 = 0.f;
#pragma unroll
            for (int r = 0; r < 8; ++r) { q0 += p[r]; q1 += p[r + 8]; }
            lsum += q0 + (full ? q1 : 0.f);
#pragma unroll
            for (int j = 0; j < 8; ++j) d[j] = pack_trunc(p[2 * j], p[2 * j + 1]);
        }
#pragma unroll
        for (int j = 0; j < 8; ++j)
            sw[j] = (unsigned)__shfl_xor((int)d[j], 32);

        // PV kv-half 0 (kv16 = 2t)
        {
            int4 bi = h ? make_int4((int)sw[2], (int)sw[3], (int)d[2], (int)d[3])
                        : make_int4((int)d[0], (int)d[1], (int)sw[0], (int)sw[1]);
            bf16x8 bf = __builtin_bit_cast(bf16x8, bi);
            __builtin_amdgcn_s_setprio(1);
            a0 = __builtin_amdgcn_mfma_f32_32x32x16_bf16(v0[0], bf, a0, 0, 0, 0);
            a1 = __builtin_amdgcn_mfma_f32_32x32x16_bf16(v0[1], bf, a1, 0, 0, 0);
            a2 = __builtin_amdgcn_mfma_f32_32x32x16_bf16(v0[2], bf, a2, 0, 0, 0);
            __builtin_amdgcn_s_setprio(0);
        }
        // PV kv-half 1 (kv16 = 2t+1; tile 24's half 1 is all pad -> skip)
        if (full) {
            int4 bi = h ? make_int4((int)sw[6], (int)sw[7], (int)d[6], (int)d[7])
                        : make_int4((int)d[4], (int)d[5], (int)sw[4], (int)sw[5]);
            bf16x8 bf = __builtin_bit_cast(bf16x8, bi);
            __builtin_amdgcn_s_setprio(1);
            a0 = __builtin_amdgcn_mfma_f32_32x32x16_bf16(v1[0], bf, a0, 0, 0, 0);
            a1 = __builtin_amdgcn_mfma_f32_32x32x16_bf16(v1[1], bf, a1, 0, 0, 0);
            a2 = __builtin_amdgcn_mfma_f32_32x32x16_bf16(v1[2], bf, a2, 0, 0, 0);
            __builtin_amdgcn_s_setprio(0);
        }
    }

    // waves 1-3: store partials (SoA [reg][lane], lane-linear => no conflicts)
    if (wid != 0) {
        float* dst = &partial[wid - 1][0][lane];
#pragma unroll
        for (int r = 0; r < 16; ++r) {
            dst[r * 64]        = a0[r];
            dst[(16 + r) * 64] = a1[r];
            dst[(32 + r) * 64] = a2[r];
        }
        dst[48 * 64] = lsum;
    }
    __syncthreads();
    if (wid == 0) {
#pragma unroll
        for (int w = 0; w < 3; ++w) {
            const float* src = &partial[w][0][lane];
#pragma unroll
            for (int r = 0; r < 16; ++r) {
                a0[r] += src[r * 64];
                a1[r] += src[(16 + r) * 64];
                a2[r] += src[(32 + r) * 64];
            }
            lsum += src[48 * 64];
        }

        lsum += __shfl_xor(lsum, 32);
        const float inv = 1.f / lsum;

        unsigned short* op = out + ((size_t)b * N_IN + qrow) * 96;
#pragma unroll
        for (int ct = 0; ct < 3; ++ct) {
            const f32x16& a = (ct == 0) ? a0 : (ct == 1 ? a1 : a2);
#pragma unroll
            for (int gblk = 0; gblk < 4; ++gblk) {
                int ch = ct * 32 + gblk * 8 + 4 * h;
                ushort4 q4 = *reinterpret_cast<const ushort4*>(qptr + ch);
                uint2 pr;
                pr.x = pack_bf16(a[gblk * 4 + 0] * inv + bf16_to_f32(q4.x),
                                 a[gblk * 4 + 1] * inv + bf16_to_f32(q4.y));
                pr.y = pack_bf16(a[gblk * 4 + 2] * inv + bf16_to_f32(q4.z),
                                 a[gblk * 4 + 3] * inv + bf16_to_f32(q4.w));
                *reinterpret_cast<uint2*>(op + ch) = pr;
            }
        }
    }
}

// ---------------------------------------------------------------------------
extern "C" void kernel_launch(void* const* d_in, const int* in_sizes, int n_in,
                              void* d_out, int out_size, void* d_ws, size_t ws_size,
                              hipStream_t stream)
{
    const float* x     = (const float*)d_in[0];
    const float* Wqkv  = (const float*)d_in[1];
    const float* bqkv  = (const float*)d_in[2];
    const float* pqw   = (const float*)d_in[3];
    const float* gq    = (const float*)d_in[4];
    const float* betq  = (const float*)d_in[5];
    const float* pkw   = (const float*)d_in[6];
    const float* gk    = (const float*)d_in[7];
    const float* betk  = (const float*)d_in[8];
    const float* pvw   = (const float*)d_in[9];
    const float* gv    = (const float*)d_in[10];
    const float* betv  = (const float*)d_in[11];
    const float* Wproj = (const float*)d_in[12];
    const float* bproj = (const float*)d_in[13];
    float* outp = (float*)d_out;

    char* ws = (char*)d_ws;
    const size_t QB    = (size_t)BATCH * N_IN * 96 * sizeof(short);       // 19.27 MB
    const size_t FRAGB = (size_t)BATCH * FRAG_ELEMS * sizeof(short);      // 5.31 MB
    unsigned short* qb   = (unsigned short*)(ws);
    unsigned short* kbuf = (unsigned short*)(ws + QB);
    unsigned short* vbuf = (unsigned short*)(ws + 2 * QB);
    unsigned short* qpb  = (unsigned short*)(ws + 3 * QB);
    unsigned short* Kfr  = (unsigned short*)(ws + 4 * QB);
    unsigned short* Vfr  = (unsigned short*)(ws + 4 * QB + FRAGB);
    unsigned short* wqf  = (unsigned short*)(ws + 4 * QB + 2 * FRAGB);
    unsigned short* wpf  = (unsigned short*)(ws + 4 * QB + 2 * FRAGB + 56320);
    float*          wpool = (float*)(ws + 4 * QB + 2 * FRAGB + 56320 + 18432);
    unsigned short* attn_out = qb;   // qb dead after pool_q

    const int T = BATCH * N_IN;      // 100352 = 256 * 392

    const float SC = 0.1020620726159658f * 1.4426950408889634f; // scale*log2e

    // 0. one-time weight prep (GEMM frags + pool transposes)
    wprep_kernel<<<29, 256, 0, stream>>>(Wqkv, Wproj, pqw, pkw, pvw, wqf, wpf, wpool);
    // 1. QKV projection (MFMA) -> q,k,v bf16 [B][3136][96]
    gemm2_kernel<18, false, false><<<T / 256, 256, 0, stream>>>(
        x, wqf, bqkv, qb, kbuf, vbuf);
    // 2-4. pool v4 (conv+LN): q row-major; K/V straight to MFMA-frag order
    pool_ln4_kernel<0, 1><<<T / 16, 192, 0, stream>>>(
        qb, wpool, gq, betq, qpb, 56, 56, N_IN, 1.0f);
    pool_ln4_kernel<1, 2><<<(BATCH * LKV_PAD) / 16, 192, 0, stream>>>(
        kbuf, wpool + 864, gk, betk, Kfr, 28, 28, LKV_PAD, SC);
    pool_ln4_kernel<2, 2><<<(BATCH * LKV_PAD) / 16, 192, 0, stream>>>(
        vbuf, wpool + 1728, gv, betv, Vfr, 28, 28, LKV_PAD, 1.0f);
    // 5. MFMA attention v6 (kv-split, 4 waves/block) + residual
    attn_mfma6_kernel<<<3136, 256, 0, stream>>>(qpb, Kfr, Vfr, attn_out);
    // 6. output projection (MFMA, fp32 out)
    gemm2_kernel<6, true, true><<<T / 256, 256, 0, stream>>>(
        attn_out, wpf, bproj, outp, nullptr, nullptr);
}

// Round 10
// 151.033 us; speedup vs baseline: 1.2771x; 1.2771x over previous
//
#include <hip/hip_runtime.h>
#include <hip/hip_bf16.h>
#include <cmath>

#define BATCH 32
#define H_IN 56
#define W_IN 56
#define N_IN (H_IN * W_IN)   // 3136
#define LKV 784              // 28*28 pooled kv length
#define LKV_PAD 864          // 27 tiles of 32
#define FRAG_ELEMS 82944     // per-batch K/V frag buffer elems (27*6*512)

typedef short bf16x8 __attribute__((ext_vector_type(8)));
typedef float f32x4 __attribute__((ext_vector_type(4)));
typedef float f32x16 __attribute__((ext_vector_type(16)));

__device__ __forceinline__ unsigned pack_bf16(float a, float b) {
    unsigned ua = __builtin_bit_cast(unsigned, a);
    unsigned ub = __builtin_bit_cast(unsigned, b);
    ua = (ua + 0x7FFFu + ((ua >> 16) & 1u)) >> 16;
    ub = (ub + 0x7FFFu + ((ub >> 16) & 1u)) >> 16;
    return ua | (ub << 16);
}

__device__ __forceinline__ unsigned short cvt_bf16(float a) {
    unsigned ua = __builtin_bit_cast(unsigned, a);
    return (unsigned short)((ua + 0x7FFFu + ((ua >> 16) & 1u)) >> 16);
}

__device__ __forceinline__ float bf16_to_f32(unsigned short u) {
    unsigned v = ((unsigned)u) << 16;
    return __builtin_bit_cast(float, v);
}

__device__ __forceinline__ float bflo(unsigned u) {
    return __builtin_bit_cast(float, u << 16);
}
__device__ __forceinline__ float bfhi(unsigned u) {
    return __builtin_bit_cast(float, u & 0xFFFF0000u);
}

// [lo16 = trunc-bf16(a), hi16 = trunc-bf16(b)] in one v_perm
__device__ __forceinline__ unsigned pack_trunc(float a, float b) {
    return __builtin_amdgcn_perm(__builtin_bit_cast(unsigned, b),
                                 __builtin_bit_cast(unsigned, a), 0x07060302u);
}

__device__ __forceinline__ f32x16 zero16() {
    f32x16 z;
#pragma unroll
    for (int i = 0; i < 16; ++i) z[i] = 0.f;
    return z;
}

// ---------------------------------------------------------------------------
// One-time weight prep:
//  idx <  3456 : Wqkv fp32 [288][96] -> bf16 A-frag order (54 frags)
//  idx <  4608 : Wproj fp32 [96][96] -> bf16 A-frag order (18 frags)
//  idx <  7200 : pool conv weights [96][9] -> transposed fp32 [3][9][96]
// ---------------------------------------------------------------------------
__global__ __launch_bounds__(256) void wprep_kernel(
    const float* __restrict__ Wqkv, const float* __restrict__ Wproj,
    const float* __restrict__ pqw, const float* __restrict__ pkw,
    const float* __restrict__ pvw,
    unsigned short* __restrict__ wq, unsigned short* __restrict__ wp,
    float* __restrict__ wpool)
{
    int idx = blockIdx.x * 256 + threadIdx.x;
    if (idx < 4608) {
        const float* src; unsigned short* dst; int li;
        if (idx < 3456) { src = Wqkv; dst = wq; li = idx; }
        else            { src = Wproj; dst = wp; li = idx - 3456; }
        int frag = li >> 6, ln = li & 63;
        int ct = frag / 3, kkb = frag % 3;
        int ch = ct * 16 + (ln & 15);
        int k0 = kkb * 32 + (ln >> 4) * 8;
        const float* s = src + ch * 96 + k0;
        float4 v0 = *reinterpret_cast<const float4*>(s);
        float4 v1 = *reinterpret_cast<const float4*>(s + 4);
        uint4 o;
        o.x = pack_bf16(v0.x, v0.y); o.y = pack_bf16(v0.z, v0.w);
        o.z = pack_bf16(v1.x, v1.y); o.w = pack_bf16(v1.z, v1.w);
        *reinterpret_cast<uint4*>(dst + (size_t)li * 8) = o;
    } else if (idx < 7200) {
        int li = idx - 4608;               // 0..2591
        int which = li / 864, r = li % 864;
        int tap = r / 96, c = r % 96;
        const float* src = (which == 0) ? pqw : (which == 1 ? pkw : pvw);
        wpool[which * 864 + tap * 96 + c] = src[c * 9 + tap];
    }
}

// ---------------------------------------------------------------------------
// MFMA GEMM v2: out[t][n] = sum_k X[t][k]*W[n][k] + bias[n]
// 256 thr / 4 waves; 256 tokens per block (64/wave = 4 iters x 16).
// ---------------------------------------------------------------------------
template <int NCT, bool IN_BF16, bool OUT_F32>
__global__ __launch_bounds__(256, 2) void gemm2_kernel(
    const void* __restrict__ Xv, const unsigned short* __restrict__ Wfr,
    const float* __restrict__ bias, void* __restrict__ o0,
    void* __restrict__ o1, void* __restrict__ o2)
{
    __shared__ unsigned short Wl[NCT * 192 * 8];
    const int tid = threadIdx.x;
    const int wid = tid >> 6, lane = tid & 63;
    const int lo16 = lane & 15, hi = lane >> 4;

    for (int idx = tid; idx < NCT * 192; idx += 256)
        *reinterpret_cast<int4*>(&Wl[idx * 8]) =
            *reinterpret_cast<const int4*>(Wfr + (size_t)idx * 8);

    const size_t tok0 = (size_t)blockIdx.x * 256 + wid * 64;
    bf16x8 xb[12];
#pragma unroll
    for (int it = 0; it < 4; ++it) {
        size_t t = tok0 + it * 16 + lo16;
#pragma unroll
        for (int kkb = 0; kkb < 3; ++kkb) {
            if constexpr (IN_BF16) {
                xb[it * 3 + kkb] = *reinterpret_cast<const bf16x8*>(
                    (const unsigned short*)Xv + t * 96 + kkb * 32 + hi * 8);
            } else {
                const float* xp = (const float*)Xv + t * 96 + kkb * 32 + hi * 8;
                float4 a = *reinterpret_cast<const float4*>(xp);
                float4 c = *reinterpret_cast<const float4*>(xp + 4);
                uint4 u;
                u.x = pack_bf16(a.x, a.y); u.y = pack_bf16(a.z, a.w);
                u.z = pack_bf16(c.x, c.y); u.w = pack_bf16(c.z, c.w);
                xb[it * 3 + kkb] = __builtin_bit_cast(bf16x8, u);
            }
        }
    }
    __syncthreads();

#pragma unroll
    for (int ct = 0; ct < NCT; ++ct) {
        bf16x8 wf[3];
#pragma unroll
        for (int kkb = 0; kkb < 3; ++kkb)
            wf[kkb] = *reinterpret_cast<const bf16x8*>(&Wl[((ct * 3 + kkb) * 64 + lane) * 8]);
        const int chb = ct * 16 + hi * 4;
        float4 bv = *reinterpret_cast<const float4*>(bias + chb);
#pragma unroll
        for (int it = 0; it < 4; ++it) {
            f32x4 a = (f32x4){0.f, 0.f, 0.f, 0.f};
#pragma unroll
            for (int kkb = 0; kkb < 3; ++kkb)
                a = __builtin_amdgcn_mfma_f32_16x16x32_bf16(wf[kkb], xb[it * 3 + kkb], a, 0, 0, 0);
            size_t t = tok0 + it * 16 + lo16;
            float r0 = a[0] + bv.x, r1 = a[1] + bv.y;
            float r2 = a[2] + bv.z, r3 = a[3] + bv.w;
            if constexpr (OUT_F32) {
                *reinterpret_cast<float4*>((float*)o0 + t * 96 + chb) =
                    make_float4(r0, r1, r2, r3);
            } else {
                unsigned short* ob =
                    (unsigned short*)((ct < 6) ? o0 : (ct < 12 ? o1 : o2));
                int lch = (ct % 6) * 16 + hi * 4;
                uint2 p;
                p.x = pack_bf16(r0, r1);
                p.y = pack_bf16(r2, r3);
                *reinterpret_cast<uint2*>(ob + t * 96 + lch) = p;
            }
        }
    }
}

// ---------------------------------------------------------------------------
// Pool v4: depthwise 3x3 conv (pad 1) + LayerNorm, bf16 in / bf16 out.
// Block = 192 threads = 16 tokens x 12 chunk-threads (8 ch each).
// OMODE 0: row-major [B][Lp][96] (q). OMODE 1: K MFMA-frag order.
// OMODE 2: V^T MFMA-frag order. For OMODE 1/2 the token space is padded to
// LpPad=864/batch; pad tokens write ZERO frags (consumed as masked pads).
// ---------------------------------------------------------------------------
template <int OMODE, int STRIDE>
__global__ __launch_bounds__(192) void pool_ln4_kernel(
    const unsigned short* __restrict__ in, const float* __restrict__ pwt,
    const float* __restrict__ g, const float* __restrict__ beta,
    unsigned short* __restrict__ out, int Hp, int Wp, int LpPad, float oscale)
{
    __shared__ float2 part[192];
    __shared__ float2 mrs[16];
    const int tid = threadIdx.x;
    const int tok_l = tid / 12, c8 = tid % 12;
    const int gt = blockIdx.x * 16 + tok_l;
    const int Lp = Hp * Wp;
    const int b = gt / LpPad, rem = gt % LpPad;
    const bool pad = (rem >= Lp);
    const int yo = rem / Wp, xo = rem % Wp;

    float wt[9][8];
#pragma unroll
    for (int tap = 0; tap < 9; ++tap) {
        float4 w0 = *reinterpret_cast<const float4*>(pwt + tap * 96 + c8 * 8);
        float4 w1 = *reinterpret_cast<const float4*>(pwt + tap * 96 + c8 * 8 + 4);
        wt[tap][0] = w0.x; wt[tap][1] = w0.y; wt[tap][2] = w0.z; wt[tap][3] = w0.w;
        wt[tap][4] = w1.x; wt[tap][5] = w1.y; wt[tap][6] = w1.z; wt[tap][7] = w1.w;
    }

    float acc[8];
#pragma unroll
    for (int j = 0; j < 8; ++j) acc[j] = 0.f;

    const unsigned short* ib = in + (size_t)b * (H_IN * W_IN * 96) + c8 * 8;
#pragma unroll
    for (int dy = 0; dy < 3; ++dy) {
        const int iy = yo * STRIDE + dy - 1;
        if ((unsigned)iy < (unsigned)H_IN) {
#pragma unroll
            for (int dx = 0; dx < 3; ++dx) {
                const int ix = xo * STRIDE + dx - 1;
                if ((unsigned)ix < (unsigned)W_IN) {
                    const int tap = dy * 3 + dx;
                    uint4 d = *reinterpret_cast<const uint4*>(
                        ib + ((size_t)iy * W_IN + ix) * 96);
                    acc[0] += bflo(d.x) * wt[tap][0];
                    acc[1] += bfhi(d.x) * wt[tap][1];
                    acc[2] += bflo(d.y) * wt[tap][2];
                    acc[3] += bfhi(d.y) * wt[tap][3];
                    acc[4] += bflo(d.z) * wt[tap][4];
                    acc[5] += bfhi(d.z) * wt[tap][5];
                    acc[6] += bflo(d.w) * wt[tap][6];
                    acc[7] += bfhi(d.w) * wt[tap][7];
                }
            }
        }
    }

    float s = 0.f, s2 = 0.f;
#pragma unroll
    for (int j = 0; j < 8; ++j) { s += acc[j]; s2 += acc[j] * acc[j]; }
    part[tid] = make_float2(s, s2);
    __syncthreads();
    if (tid < 16) {
        float a = 0.f, q = 0.f;
#pragma unroll
        for (int j = 0; j < 12; ++j) {
            float2 p = part[tid * 12 + j];
            a += p.x; q += p.y;
        }
        float mu = a * (1.f / 96.f);
        float var = q * (1.f / 96.f) - mu * mu;
        mrs[tid] = make_float2(mu, rsqrtf(var + 1e-6f));
    }
    __syncthreads();
    const float mu = mrs[tok_l].x, rstd = mrs[tok_l].y;

    float4 g0 = *reinterpret_cast<const float4*>(g + c8 * 8);
    float4 g1 = *reinterpret_cast<const float4*>(g + c8 * 8 + 4);
    float4 b0 = *reinterpret_cast<const float4*>(beta + c8 * 8);
    float4 b1 = *reinterpret_cast<const float4*>(beta + c8 * 8 + 4);
    float r[8];
    r[0] = (acc[0] - mu) * rstd * (g0.x * oscale) + b0.x * oscale;
    r[1] = (acc[1] - mu) * rstd * (g0.y * oscale) + b0.y * oscale;
    r[2] = (acc[2] - mu) * rstd * (g0.z * oscale) + b0.z * oscale;
    r[3] = (acc[3] - mu) * rstd * (g0.w * oscale) + b0.w * oscale;
    r[4] = (acc[4] - mu) * rstd * (g1.x * oscale) + b1.x * oscale;
    r[5] = (acc[5] - mu) * rstd * (g1.y * oscale) + b1.y * oscale;
    r[6] = (acc[6] - mu) * rstd * (g1.z * oscale) + b1.z * oscale;
    r[7] = (acc[7] - mu) * rstd * (g1.w * oscale) + b1.w * oscale;
    if (OMODE != 0 && pad) {
#pragma unroll
        for (int j = 0; j < 8; ++j) r[j] = 0.f;
    }

    if constexpr (OMODE == 0) {
        uint4 o;
        o.x = pack_bf16(r[0], r[1]); o.y = pack_bf16(r[2], r[3]);
        o.z = pack_bf16(r[4], r[5]); o.w = pack_bf16(r[6], r[7]);
        *reinterpret_cast<uint4*>(out + (size_t)gt * 96 + c8 * 8) = o;
    } else if constexpr (OMODE == 1) {
        // K frag order: frag(t=kv/32, kkb), lane = (kv&31)|(hi<<5); 16B/thread
        int t = rem >> 5, kkb = c8 >> 1, hi = c8 & 1;
        int ln = (rem & 31) | (hi << 5);
        uint4 o;
        o.x = pack_bf16(r[0], r[1]); o.y = pack_bf16(r[2], r[3]);
        o.z = pack_bf16(r[4], r[5]); o.w = pack_bf16(r[6], r[7]);
        *reinterpret_cast<uint4*>(out + (size_t)b * FRAG_ELEMS +
                                  ((size_t)(t * 6 + kkb) * 64 + ln) * 8) = o;
    } else {
        // V^T frag order: frag(kv16, ct), lane=(ch&31)|(lh<<5), elem = kv&7
        int kv16 = rem >> 4, e = rem & 7, lh = (rem >> 3) & 1;
#pragma unroll
        for (int j = 0; j < 8; ++j) {
            int j8 = c8 * 8 + j;
            int ct = j8 >> 5;
            int ln = (j8 & 31) | (lh << 5);
            out[(size_t)b * FRAG_ELEMS + ((size_t)(kv16 * 3 + ct) * 64 + ln) * 8 + e] =
                cvt_bf16(r[j]);
        }
    }
}

// ---------------------------------------------------------------------------
// MFMA flash attention v7 + residual (bf16 out). Barrier-free, one wave per
// 32 q rows (3136 independent waves). v5 minus s_setprio (scheduling fences
// that blocked load hoisting; T5 null for non-phase-split kernels) plus an
// explicit 2-stage register double-buffer: tile t+1's K/V frag loads issue
// a full compute phase ahead, hiding L2 latency behind QK/softmax/PV.
// ---------------------------------------------------------------------------
#define ATT_LOAD(KF, V0, V1, T)                                               \
    {                                                                         \
        _Pragma("unroll") for (int i_ = 0; i_ < 6; ++i_)                      \
            KF[i_] = *reinterpret_cast<const bf16x8*>(                        \
                Kb + ((size_t)((T) * 6 + i_) * 64 + lane) * 8);               \
        _Pragma("unroll") for (int c_ = 0; c_ < 3; ++c_) {                    \
            V0[c_] = *reinterpret_cast<const bf16x8*>(                        \
                Vb + ((size_t)((2 * (T)) * 3 + c_) * 64 + lane) * 8);         \
            V1[c_] = *reinterpret_cast<const bf16x8*>(                        \
                Vb + ((size_t)((2 * (T) + 1) * 3 + c_) * 64 + lane) * 8);     \
        }                                                                     \
    }

#define ATT_COMPUTE(KF, V0, V1, FULL)                                         \
    {                                                                         \
        f32x16 s = zero16();                                                  \
        _Pragma("unroll") for (int k_ = 0; k_ < 6; ++k_)                      \
            s = __builtin_amdgcn_mfma_f32_32x32x16_bf16(KF[k_], qf[k_], s, 0, 0, 0); \
        float p[16];                                                          \
        _Pragma("unroll") for (int r_ = 0; r_ < 16; ++r_) {                   \
            float e_ = __builtin_amdgcn_exp2f(s[r_]);                         \
            p[r_] = __builtin_bit_cast(float,                                 \
                      __builtin_bit_cast(unsigned, e_) & 0xFFFF0000u);        \
        }                                                                     \
        float q0_ = 0.f, q1_ = 0.f;                                           \
        _Pragma("unroll") for (int r_ = 0; r_ < 8; ++r_) {                    \
            q0_ += p[r_]; q1_ += p[r_ + 8];                                   \
        }                                                                     \
        lsum += q0_ + ((FULL) ? q1_ : 0.f);                                   \
        unsigned d[8], sw[8];                                                 \
        _Pragma("unroll") for (int j_ = 0; j_ < 8; ++j_)                      \
            d[j_] = pack_trunc(p[2 * j_], p[2 * j_ + 1]);                     \
        _Pragma("unroll") for (int j_ = 0; j_ < 8; ++j_)                      \
            sw[j_] = (unsigned)__shfl_xor((int)d[j_], 32);                    \
        {                                                                     \
            int4 bi = h ? make_int4((int)sw[2], (int)sw[3], (int)d[2], (int)d[3]) \
                        : make_int4((int)d[0], (int)d[1], (int)sw[0], (int)sw[1]); \
            bf16x8 bf = __builtin_bit_cast(bf16x8, bi);                       \
            a0 = __builtin_amdgcn_mfma_f32_32x32x16_bf16(V0[0], bf, a0, 0, 0, 0); \
            a1 = __builtin_amdgcn_mfma_f32_32x32x16_bf16(V0[1], bf, a1, 0, 0, 0); \
            a2 = __builtin_amdgcn_mfma_f32_32x32x16_bf16(V0[2], bf, a2, 0, 0, 0); \
        }                                                                     \
        if (FULL) {                                                           \
            int4 bi = h ? make_int4((int)sw[6], (int)sw[7], (int)d[6], (int)d[7]) \
                        : make_int4((int)d[4], (int)d[5], (int)sw[4], (int)sw[5]); \
            bf16x8 bf = __builtin_bit_cast(bf16x8, bi);                       \
            a0 = __builtin_amdgcn_mfma_f32_32x32x16_bf16(V1[0], bf, a0, 0, 0, 0); \
            a1 = __builtin_amdgcn_mfma_f32_32x32x16_bf16(V1[1], bf, a1, 0, 0, 0); \
            a2 = __builtin_amdgcn_mfma_f32_32x32x16_bf16(V1[2], bf, a2, 0, 0, 0); \
        }                                                                     \
    }

__global__ __launch_bounds__(64) void attn_mfma7_kernel(
    const unsigned short* __restrict__ qpl, const unsigned short* __restrict__ Kf,
    const unsigned short* __restrict__ Vf, unsigned short* __restrict__ out)
{
    const int bid = blockIdx.x;                    // 0..3135
    const int swz = (bid & 7) * 392 + (bid >> 3);  // XCD grouping (3136%8==0)
    const int b = swz / 98, qblk = swz % 98;
    const int lane = threadIdx.x;
    const int l31 = lane & 31, h = lane >> 5;

    const int qrow = qblk * 32 + l31;
    const unsigned short* qptr = qpl + ((size_t)b * N_IN + qrow) * 96;
    bf16x8 qf[6];
#pragma unroll
    for (int kkb = 0; kkb < 6; ++kkb)
        qf[kkb] = *reinterpret_cast<const bf16x8*>(qptr + kkb * 16 + h * 8);

    f32x16 a0 = zero16(), a1 = zero16(), a2 = zero16();
    float lsum = 0.f;

    const unsigned short* Kb = Kf + (size_t)b * FRAG_ELEMS;
    const unsigned short* Vb = Vf + (size_t)b * FRAG_ELEMS;

    bf16x8 kA[6], vA0[3], vA1[3];
    bf16x8 kB[6], vB0[3], vB1[3];

    ATT_LOAD(kA, vA0, vA1, 0);
    for (int t = 0; t < 24; t += 2) {
        ATT_LOAD(kB, vB0, vB1, t + 1);
        ATT_COMPUTE(kA, vA0, vA1, true);
        ATT_LOAD(kA, vA0, vA1, t + 2);
        ATT_COMPUTE(kB, vB0, vB1, true);
    }
    ATT_COMPUTE(kA, vA0, vA1, false);   // tile 24: kv-half 1 is all pad

    lsum += __shfl_xor(lsum, 32);
    const float inv = 1.f / lsum;

    unsigned short* op = out + ((size_t)b * N_IN + qrow) * 96;
#pragma unroll
    for (int ct = 0; ct < 3; ++ct) {
        const f32x16& a = (ct == 0) ? a0 : (ct == 1 ? a1 : a2);
#pragma unroll
        for (int gblk = 0; gblk < 4; ++gblk) {
            int ch = ct * 32 + gblk * 8 + 4 * h;
            ushort4 q4 = *reinterpret_cast<const ushort4*>(qptr + ch);
            uint2 pr;
            pr.x = pack_bf16(a[gblk * 4 + 0] * inv + bf16_to_f32(q4.x),
                             a[gblk * 4 + 1] * inv + bf16_to_f32(q4.y));
            pr.y = pack_bf16(a[gblk * 4 + 2] * inv + bf16_to_f32(q4.z),
                             a[gblk * 4 + 3] * inv + bf16_to_f32(q4.w));
            *reinterpret_cast<uint2*>(op + ch) = pr;
        }
    }
}

// ---------------------------------------------------------------------------
extern "C" void kernel_launch(void* const* d_in, const int* in_sizes, int n_in,
                              void* d_out, int out_size, void* d_ws, size_t ws_size,
                              hipStream_t stream)
{
    const float* x     = (const float*)d_in[0];
    const float* Wqkv  = (const float*)d_in[1];
    const float* bqkv  = (const float*)d_in[2];
    const float* pqw   = (const float*)d_in[3];
    const float* gq    = (const float*)d_in[4];
    const float* betq  = (const float*)d_in[5];
    const float* pkw   = (const float*)d_in[6];
    const float* gk    = (const float*)d_in[7];
    const float* betk  = (const float*)d_in[8];
    const float* pvw   = (const float*)d_in[9];
    const float* gv    = (const float*)d_in[10];
    const float* betv  = (const float*)d_in[11];
    const float* Wproj = (const float*)d_in[12];
    const float* bproj = (const float*)d_in[13];
    float* outp = (float*)d_out;

    char* ws = (char*)d_ws;
    const size_t QB    = (size_t)BATCH * N_IN * 96 * sizeof(short);       // 19.27 MB
    const size_t FRAGB = (size_t)BATCH * FRAG_ELEMS * sizeof(short);      // 5.31 MB
    unsigned short* qb   = (unsigned short*)(ws);
    unsigned short* kbuf = (unsigned short*)(ws + QB);
    unsigned short* vbuf = (unsigned short*)(ws + 2 * QB);
    unsigned short* qpb  = (unsigned short*)(ws + 3 * QB);
    unsigned short* Kfr  = (unsigned short*)(ws + 4 * QB);
    unsigned short* Vfr  = (unsigned short*)(ws + 4 * QB + FRAGB);
    unsigned short* wqf  = (unsigned short*)(ws + 4 * QB + 2 * FRAGB);
    unsigned short* wpf  = (unsigned short*)(ws + 4 * QB + 2 * FRAGB + 56320);
    float*          wpool = (float*)(ws + 4 * QB + 2 * FRAGB + 56320 + 18432);
    unsigned short* attn_out = qb;   // qb dead after pool_q

    const int T = BATCH * N_IN;      // 100352 = 256 * 392

    const float SC = 0.1020620726159658f * 1.4426950408889634f; // scale*log2e

    // 0. one-time weight prep (GEMM frags + pool transposes)
    wprep_kernel<<<29, 256, 0, stream>>>(Wqkv, Wproj, pqw, pkw, pvw, wqf, wpf, wpool);
    // 1. QKV projection (MFMA) -> q,k,v bf16 [B][3136][96]
    gemm2_kernel<18, false, false><<<T / 256, 256, 0, stream>>>(
        x, wqf, bqkv, qb, kbuf, vbuf);
    // 2-4. pool v4 (conv+LN): q row-major; K/V straight to MFMA-frag order
    pool_ln4_kernel<0, 1><<<T / 16, 192, 0, stream>>>(
        qb, wpool, gq, betq, qpb, 56, 56, N_IN, 1.0f);
    pool_ln4_kernel<1, 2><<<(BATCH * LKV_PAD) / 16, 192, 0, stream>>>(
        kbuf, wpool + 864, gk, betk, Kfr, 28, 28, LKV_PAD, SC);
    pool_ln4_kernel<2, 2><<<(BATCH * LKV_PAD) / 16, 192, 0, stream>>>(
        vbuf, wpool + 1728, gv, betv, Vfr, 28, 28, LKV_PAD, 1.0f);
    // 5. MFMA attention v7 (barrier-free, double-buffered, no setprio)
    attn_mfma7_kernel<<<3136, 64, 0, stream>>>(qpb, Kfr, Vfr, attn_out);
    // 6. output projection (MFMA, fp32 out)
    gemm2_kernel<6, true, true><<<T / 256, 256, 0, stream>>>(
        attn_out, wpf, bproj, outp, nullptr, nullptr);
}